// Round 2
// baseline (4328.461 us; speedup 1.0000x reference)
//
#include <hip/hip_runtime.h>
#include <stdint.h>

// T=512, B=32, I=1024, H=1024, G=4H=4096
// out: [512][32][2048] fp32 then hf[32][1024], cf, hb, cb  (total 33685504 f32)

using short8 = __attribute__((ext_vector_type(8))) short;   // 8 bf16
using f32x4  = __attribute__((ext_vector_type(4))) float;
using f32x2  = __attribute__((ext_vector_type(2))) float;
using f32x16 = __attribute__((ext_vector_type(16))) float;
using h2f    = __attribute__((ext_vector_type(2))) _Float16;

typedef unsigned int uint;
typedef unsigned short ushort;
typedef unsigned long long ull;

typedef const __attribute__((address_space(1))) void cg_void;
typedef __attribute__((address_space(3))) void lds_void;

// ---------------- ws layout (bytes) ----------------
// ROUND-2: hbuf/flags are 8-way REPLICATED to spread the hot 64KB exchange
// region (4MB/step of sc1 reads from 64 CUs) across 8x the LLC slices.
#define OFF_XB      0ull            // x as bf16: 16777216 * 2 = 33554432
#define OFF_WIH_F   33554432ull     // 4096*1024*2 = 8388608
#define OFF_WIH_B   41943040ull
#define OFF_WHH_F   50331648ull
#define OFF_WHH_B   58720256ull
#define OFF_BSUM_F  67108864ull     // 4096 * 4
#define OFF_BSUM_B  67125248ull
#define OFF_HBUF    67141632ull     // 8 replicas * (2 dir * 2 parity * 32*1024 * 2B) = 8*262144
#define OFF_CBUF    69238784ull     // 2 * 32*1024 * 4B = 262144
#define OFF_FLAGS   69500928ull     // 8 replicas * 64 uints = 2048B
#define OFF_XG      69502976ull     // fp16 xg: 2 * csteps*32*4096*2

#define REPL        8
#define REPL_U32    65536           // uints per hbuf replica (262144B/4)
#define REPL_U16    131072          // ushorts per hbuf replica

__device__ __forceinline__ ushort f2bf(float f) {
    uint u = __float_as_uint(f);
    u += 0x7fffu + ((u >> 16) & 1u);   // RNE
    return (ushort)(u >> 16);
}
__device__ __forceinline__ float sigmoidf_(float x) { return 1.0f / (1.0f + expf(-x)); }

// ---------------- prep: fp32 -> bf16 converts, bias sums, h0, flags ----------------
__global__ __launch_bounds__(256) void prep_kernel(
    const float* __restrict__ x,
    const float* __restrict__ wih_f, const float* __restrict__ whh_f,
    const float* __restrict__ bih_f, const float* __restrict__ bhh_f,
    const float* __restrict__ wih_b, const float* __restrict__ whh_b,
    const float* __restrict__ bih_b, const float* __restrict__ bhh_b,
    const float* __restrict__ h0f, const float* __restrict__ h0b,
    char* __restrict__ ws)
{
    int r = blockIdx.x * 256 + threadIdx.x;
    const int n_x = 16777216, n_w = 4194304;
    if (r < n_x) { ((ushort*)(ws + OFF_XB))[r] = f2bf(x[r]); return; }
    r -= n_x;
    if (r < n_w) { ((ushort*)(ws + OFF_WIH_F))[r] = f2bf(wih_f[r]); return; }
    r -= n_w;
    if (r < n_w) { ((ushort*)(ws + OFF_WIH_B))[r] = f2bf(wih_b[r]); return; }
    r -= n_w;
    if (r < n_w) { ((ushort*)(ws + OFF_WHH_F))[r] = f2bf(whh_f[r]); return; }
    r -= n_w;
    if (r < n_w) { ((ushort*)(ws + OFF_WHH_B))[r] = f2bf(whh_b[r]); return; }
    r -= n_w;
    if (r < 4096) { ((float*)(ws + OFF_BSUM_F))[r] = bih_f[r] + bhh_f[r]; return; }
    r -= 4096;
    if (r < 4096) { ((float*)(ws + OFF_BSUM_B))[r] = bih_b[r] + bhh_b[r]; return; }
    r -= 4096;
    if (r < 32768) {                       // dir0, parity0 -> all replicas
        ushort v = f2bf(h0f[r]);
#pragma unroll
        for (int rep = 0; rep < REPL; ++rep)
            ((ushort*)(ws + OFF_HBUF))[rep * REPL_U16 + r] = v;
        return;
    }
    r -= 32768;
    if (r < 32768) {                       // dir1, parity0 -> all replicas
        ushort v = f2bf(h0b[r]);
#pragma unroll
        for (int rep = 0; rep < REPL; ++rep)
            ((ushort*)(ws + OFF_HBUF))[rep * REPL_U16 + 2 * 32768 + r] = v;
        return;
    }
    r -= 32768;
    if (r < 64 * REPL) { ((uint*)(ws + OFF_FLAGS))[r] = 0u; return; }
}

// ---------------- xg GEMM: xg[slot*32+b][g] = sum_i x[t][b][i] * Wih[g][i] ----------------
__global__ __launch_bounds__(256) void gemm_xg(
    const ushort* __restrict__ xb,
    const ushort* __restrict__ wihf, const ushort* __restrict__ wihb,
    _Float16* __restrict__ xgf, _Float16* __restrict__ xgb,
    int s0)
{
    __shared__ ushort As[128 * 32];
    __shared__ ushort Bs[128 * 32];
    const int dir = blockIdx.z;
    const ushort* __restrict__ W = dir ? wihb : wihf;
    _Float16* __restrict__ xg = dir ? xgb : xgf;
    const int mBlk = blockIdx.x, nBlk = blockIdx.y;
    const int tid = threadIdx.x;
    const int w = tid >> 6, l = tid & 63;
    const int q = l >> 4, ml = l & 15;

    f32x4 acc[4][4];
    const f32x4 zero = {0.f, 0.f, 0.f, 0.f};
#pragma unroll
    for (int i = 0; i < 4; ++i)
#pragma unroll
        for (int j = 0; j < 4; ++j) acc[i][j] = zero;

    for (int kb = 0; kb < 32; ++kb) {
#pragma unroll
        for (int it = 0; it < 2; ++it) {
            int idx = tid + 256 * it;           // 0..511
            int rl = idx >> 2, kc = idx & 3;
            int gr = mBlk * 128 + rl;           // row in slot-space
            int slot = gr >> 5, bb = gr & 31;
            int t = dir ? (511 - s0 - slot) : (s0 + slot);
            const ushort* ga = xb + (size_t)(t * 32 + bb) * 1024 + kb * 32 + kc * 8;
            __builtin_amdgcn_global_load_lds((cg_void*)ga, (lds_void*)(As + idx * 8), 16, 0, 0);
            int colg = nBlk * 128 + rl;
            const ushort* gbp = W + (size_t)colg * 1024 + kb * 32 + kc * 8;
            __builtin_amdgcn_global_load_lds((cg_void*)gbp, (lds_void*)(Bs + idx * 8), 16, 0, 0);
        }
        __syncthreads();
        short8 af[4], bfr[4];
#pragma unroll
        for (int i = 0; i < 4; ++i)
            af[i] = *(const short8*)(As + ((w & 1) * 64 + i * 16 + ml) * 32 + q * 8);
#pragma unroll
        for (int j = 0; j < 4; ++j)
            bfr[j] = *(const short8*)(Bs + ((w >> 1) * 64 + j * 16 + ml) * 32 + q * 8);
#pragma unroll
        for (int i = 0; i < 4; ++i)
#pragma unroll
            for (int j = 0; j < 4; ++j)
                acc[i][j] = __builtin_amdgcn_mfma_f32_16x16x32_bf16(af[i], bfr[j], acc[i][j], 0, 0, 0);
        __syncthreads();
    }
#pragma unroll
    for (int i = 0; i < 4; ++i)
#pragma unroll
        for (int j = 0; j < 4; ++j)
#pragma unroll
            for (int rr = 0; rr < 4; ++rr) {
                int row = mBlk * 128 + (w & 1) * 64 + i * 16 + q * 4 + rr;
                int col = nBlk * 128 + (w >> 1) * 64 + j * 16 + ml;
                xg[(size_t)row * 4096 + col] = (_Float16)acc[i][j][rr];
            }
}

// ---------------- recurrence: cooperative, 64 blocks x 512 threads ----------------
// dir = bx&1, p = bx>>1 (0..31). Block owns h-cols [p*32,(p+1)*32). Wave w: gate
// nt=w&3, K-half kh=w>>2; B-frags (32 cols x 512 K) persist in 128 VGPRs/lane.
// ALL inter-block traffic uses RELAXED agent-scope atomics (sc1). Producer
// ordering: write-through h stores -> vmcnt drain -> relaxed flag post.
// ROUND-2: 8-way replicated exchange. Producers store h + flags to 8 replicas;
// consumer bx reads replica bx&7. Total read volume unchanged (64KB/block) but
// spread across 8x LLC slices; flag polling fan-in per line drops 64 -> 8.
__global__ __launch_bounds__(512, 2) void rec_kernel(
    const ushort* __restrict__ whhf, const ushort* __restrict__ whhb,
    const _Float16* __restrict__ xgf, const _Float16* __restrict__ xgb,
    const float* __restrict__ bsumf, const float* __restrict__ bsumb,
    const float* __restrict__ c0f, const float* __restrict__ c0b,
    uint* __restrict__ hbuf, float* __restrict__ cbuf,
    float* __restrict__ out, uint* __restrict__ flags,
    int s0, int csteps)
{
    __shared__ __align__(16) char lds_raw[65536];   // h-stage (64KB), overlaid by gate buf
    ushort* Hst = (ushort*)lds_raw;
    float*  gb  = (float*)lds_raw;

    const int bx = blockIdx.x;
    const int dir = bx & 1;
    const int p = bx >> 1;              // 0..31
    const int rep = bx & 7;             // this block's read replica
    const int tid = threadIdx.x;
    const int w = tid >> 6;             // 0..7
    const int l = tid & 63;
    const int half = l >> 5;
    const int m32 = l & 31;
    const int nt = w & 3;               // gate index
    const int kh = w >> 2;              // K half

    const ushort* W = dir ? whhb : whhf;
    const _Float16* xg = dir ? xgb : xgf;
    const float* bsum = dir ? bsumb : bsumf;
    uint* flr = flags + rep * 64 + dir * 32;     // replica polled by this block

    // B-frag preload: col = nt*1024 + p*32 + m32, k = kh*512 + kk*16 + half*8 + j
    const ushort* wrow = W + ((size_t)(nt * 1024 + p * 32 + m32)) * 1024 + kh * 512 + half * 8;
    short8 bfrag[32];
#pragma unroll
    for (int kk = 0; kk < 32; ++kk)
        bfrag[kk] = *(const short8*)(wrow + kk * 16);

    // elementwise identity: thread -> (batch b, col pair rp, rp+1)
    const int b = tid >> 4;             // 0..31
    const int rp = (tid & 15) * 2;      // 0,2,..,30
    const int hcol = p * 32 + rp;
    f32x2 bs[4];
#pragma unroll
    for (int g = 0; g < 4; ++g)
        bs[g] = *(const f32x2*)(bsum + g * 1024 + hcol);
    f32x2 cc;
    {
        const float* csrc = (s0 == 0) ? (dir ? c0b : c0f) : (cbuf + dir * 32768);
        cc = *(const f32x2*)(csrc + b * 1024 + hcol);
    }

    for (int s = s0; s < s0 + csteps; ++s) {
        const int slot = s - s0;
        const int t = dir ? (511 - s) : s;

        // xg for this step: issued first, hidden under flag-wait + staging + MFMA
        uint xv[4];
#pragma unroll
        for (int g = 0; g < 4; ++g)
            xv[g] = *(const uint*)(xg + ((size_t)slot * 32 + b) * 4096 + g * 1024 + hcol);

        // ---- one-shot all-producer poll on this block's replica ----
        {
            uint f = 0xFFFFFFFFu;       // lanes >=32 vacuously ready
            for (;;) {
                if (l < 32)
                    f = __hip_atomic_load(flr + l, __ATOMIC_RELAXED, __HIP_MEMORY_SCOPE_AGENT);
                if (__all(f >= (uint)s)) break;
                __builtin_amdgcn_s_sleep(1);
            }
        }
        asm volatile("" ::: "memory");

        // ---- stage h^s (parity s&1) from replica: 16 loads back-to-back ----
        const ull* h64 = (const ull*)(hbuf + (size_t)rep * REPL_U32 +
                                      (size_t)(dir * 2 + (s & 1)) * 16384);
#pragma unroll
        for (int i = 0; i < 4; ++i) {
            const int pc = w * 4 + i;
#pragma unroll
            for (int uu = 0; uu < 4; ++uu) {
                const int idx = uu * 64 + l;
                const int bb = idx >> 3, uo = idx & 7;
                ull v = __hip_atomic_load(h64 + bb * 256 + pc * 8 + uo,
                                          __ATOMIC_RELAXED, __HIP_MEMORY_SCOPE_AGENT);
                const int ch = pc * 4 + (uo >> 1);
                *(ull*)(Hst + bb * 1024 + ((ch ^ (bb & 7)) << 3) + (uo & 1) * 4) = v;
            }
        }
        __syncthreads();

        // ---- MFMA: gates[32 batch, 32 cols] partial over K-half ----
        f32x16 acce, acco;
#pragma unroll
        for (int i = 0; i < 16; ++i) { acce[i] = 0.f; acco[i] = 0.f; }
#pragma unroll
        for (int kk = 0; kk < 32; kk += 2) {
            const short8 a0 = *(const short8*)(Hst + m32 * 1024 +
                (((kh * 64 + kk * 2 + half) ^ (m32 & 7)) << 3));
            acce = __builtin_amdgcn_mfma_f32_32x32x16_bf16(a0, bfrag[kk], acce, 0, 0, 0);
            const short8 a1 = *(const short8*)(Hst + m32 * 1024 +
                (((kh * 64 + (kk + 1) * 2 + half) ^ (m32 & 7)) << 3));
            acco = __builtin_amdgcn_mfma_f32_32x32x16_bf16(a1, bfrag[kk + 1], acco, 0, 0, 0);
        }
        __syncthreads();   // all Hst reads done before gbuf overlay writes

        // ---- C-store: row=(reg&3)+8*(reg>>2)+4*half, col=m32 ----
#pragma unroll
        for (int reg = 0; reg < 16; ++reg) {
            const int row = (reg & 3) + 8 * (reg >> 2) + 4 * half;
            gb[kh * 4128 + row * 129 + nt * 32 + m32] = acce[reg] + acco[reg];
        }
        __syncthreads();

        // ---- elementwise LSTM update (2 adjacent cols, 1 batch per thread) ----
        const float* gA = gb + b * 129 + rp;
        const float* gB = gb + 4128 + b * 129 + rp;
        f32x2 G[4];
#pragma unroll
        for (int g = 0; g < 4; ++g) {
            h2f xh = __builtin_bit_cast(h2f, xv[g]);
            G[g][0] = gA[g * 32]     + gB[g * 32]     + bs[g][0] + (float)xh[0];
            G[g][1] = gA[g * 32 + 1] + gB[g * 32 + 1] + bs[g][1] + (float)xh[1];
        }
        f32x2 hh;
#pragma unroll
        for (int j = 0; j < 2; ++j) {
            float ii = sigmoidf_(G[0][j]), ff2 = sigmoidf_(G[1][j]);
            float g2 = tanhf(G[2][j]),     oo  = sigmoidf_(G[3][j]);
            cc[j] = ff2 * cc[j] + ii * g2;
            hh[j] = oo * tanhf(cc[j]);
        }
        // write-through h store to ALL replicas, then drain + barrier + flag post
        uint hp = (uint)f2bf(hh[0]) | ((uint)f2bf(hh[1]) << 16);
        {
            const size_t base = (size_t)(dir * 2 + ((s + 1) & 1)) * 16384 +
                                b * 512 + p * 16 + (tid & 15);
#pragma unroll
            for (int r = 0; r < REPL; ++r)
                __hip_atomic_store(hbuf + (size_t)r * REPL_U32 + base,
                                   hp, __ATOMIC_RELAXED, __HIP_MEMORY_SCOPE_AGENT);
        }
        asm volatile("s_waitcnt vmcnt(0)" ::: "memory");
        __syncthreads();
        if (tid == 0) {
#pragma unroll
            for (int r = 0; r < REPL; ++r)
                __hip_atomic_store(flags + r * 64 + dir * 32 + p, (uint)(s + 1),
                                   __ATOMIC_RELAXED, __HIP_MEMORY_SCOPE_AGENT);
        }

        // ---- out stores (off the critical path, nontemporal: keep L2 clean) ----
        __builtin_nontemporal_store(__builtin_bit_cast(double, hh),
            (double*)(out + (size_t)t * 65536 + b * 2048 + dir * 1024 + hcol));
        if (s == 511) {
            float* fin = out + 33554432 + dir * 65536;   // hf,cf then hb,cb
            *(f32x2*)(fin + b * 1024 + hcol) = hh;
            *(f32x2*)(fin + 32768 + b * 1024 + hcol) = cc;
        }
    }
    *(f32x2*)(cbuf + dir * 32768 + b * 1024 + hcol) = cc;
}

// ---------------- host ----------------
extern "C" void kernel_launch(void* const* d_in, const int* in_sizes, int n_in,
                              void* d_out, int out_size, void* d_ws, size_t ws_size,
                              hipStream_t stream)
{
    const float* x     = (const float*)d_in[0];
    const float* h0f   = (const float*)d_in[1];
    const float* c0f   = (const float*)d_in[2];
    const float* h0b   = (const float*)d_in[3];
    const float* c0b   = (const float*)d_in[4];
    const float* wih_f = (const float*)d_in[5];
    const float* whh_f = (const float*)d_in[6];
    const float* bih_f = (const float*)d_in[7];
    const float* bhh_f = (const float*)d_in[8];
    const float* wih_b = (const float*)d_in[9];
    const float* whh_b = (const float*)d_in[10];
    const float* bih_b = (const float*)d_in[11];
    const float* bhh_b = (const float*)d_in[12];
    float* out = (float*)d_out;
    char* ws = (char*)d_ws;

    int csteps = 16;
    const int cands[6] = {512, 256, 128, 64, 32, 16};
    for (int i = 0; i < 6; ++i) {
        size_t need = OFF_XG + 2ull * (size_t)cands[i] * 262144ull;
        if (need <= ws_size) { csteps = cands[i]; break; }
    }

    prep_kernel<<<131362, 256, 0, stream>>>(x, wih_f, whh_f, bih_f, bhh_f,
                                            wih_b, whh_b, bih_b, bhh_b, h0f, h0b, ws);

    const ushort* xb    = (const ushort*)(ws + OFF_XB);
    const ushort* wihfb = (const ushort*)(ws + OFF_WIH_F);
    const ushort* wihbb = (const ushort*)(ws + OFF_WIH_B);
    const ushort* whhfb = (const ushort*)(ws + OFF_WHH_F);
    const ushort* whhbb = (const ushort*)(ws + OFF_WHH_B);
    const float*  bsf   = (const float*)(ws + OFF_BSUM_F);
    const float*  bsb   = (const float*)(ws + OFF_BSUM_B);
    uint*   hb          = (uint*)(ws + OFF_HBUF);
    float*  cb          = (float*)(ws + OFF_CBUF);
    uint*   flagsp      = (uint*)(ws + OFF_FLAGS);
    _Float16* xgfp      = (_Float16*)(ws + OFF_XG);
    _Float16* xgbp      = (_Float16*)(ws + OFF_XG + (size_t)csteps * 262144ull);

    const int nchunks = 512 / csteps;
    for (int cidx = 0; cidx < nchunks; ++cidx) {
        int s0 = cidx * csteps;
        gemm_xg<<<dim3(csteps / 4, 32, 2), 256, 0, stream>>>(xb, wihfb, wihbb, xgfp, xgbp, s0);

        const ushort* a0 = whhfb; const ushort* a1 = whhbb;
        const _Float16* a2 = xgfp; const _Float16* a3 = xgbp;
        const float* a4 = bsf; const float* a5 = bsb;
        const float* a6 = c0f; const float* a7 = c0b;
        uint* a8 = hb; float* a9 = cb; float* a10 = out; uint* a11 = flagsp;
        int a12 = s0, a13 = csteps;
        void* args[] = {&a0, &a1, &a2, &a3, &a4, &a5, &a6, &a7, &a8, &a9, &a10, &a11, &a12, &a13};
        hipLaunchCooperativeKernel((void*)rec_kernel, dim3(64), dim3(512), args, 0, stream);
    }
}

// Round 3
// 3598.440 us; speedup vs baseline: 1.2029x; 1.2029x over previous
//
#include <hip/hip_runtime.h>
#include <stdint.h>

// T=512, B=32, I=1024, H=1024, G=4H=4096
// out: [512][32][2048] fp32 then hf[32][1024], cf, hb, cb  (total 33685504 f32)

using short8 = __attribute__((ext_vector_type(8))) short;   // 8 bf16
using f32x4  = __attribute__((ext_vector_type(4))) float;
using f32x2  = __attribute__((ext_vector_type(2))) float;
using f32x16 = __attribute__((ext_vector_type(16))) float;
using h2f    = __attribute__((ext_vector_type(2))) _Float16;

typedef unsigned int uint;
typedef unsigned short ushort;
typedef unsigned long long ull;

typedef const __attribute__((address_space(1))) void cg_void;
typedef __attribute__((address_space(3))) void lds_void;

// ---------------- ws layout (bytes) ----------------
// ROUND-3: flags/drain/replication protocol REMOVED. h exchange is per-8B-word
// self-validating: ull = (2xbf16 payload) | ((ull)step_tag << 32). Aligned 8B
// relaxed-agent stores are atomic -> tag==s guarantees valid payload. This
// removes the two serialized HBM write-through latencies per step (producer
// vmcnt(0) drain + flag post->discovery) that rounds 0-2 proved were not
// poll-latency, not LLC BW (WRITE_SIZE showed sc1 stores reach DRAM).
#define OFF_XB      0ull            // x as bf16: 16777216 * 2 = 33554432
#define OFF_WIH_F   33554432ull     // 4096*1024*2 = 8388608
#define OFF_WIH_B   41943040ull
#define OFF_WHH_F   50331648ull
#define OFF_WHH_B   58720256ull
#define OFF_BSUM_F  67108864ull     // 4096 * 4
#define OFF_BSUM_B  67125248ull
#define OFF_HBUF    67141632ull     // 2 dir * 2 parity * 16384 tagged ull = 524288
#define OFF_CBUF    67665920ull     // 2 * 32*1024 * 4B = 262144
#define OFF_XG      67928064ull     // fp16 xg: 2 * csteps*32*4096*2

// hbuf word layout: buffer (dir*2 + parity) * 16384 words; word index within
// buffer = batch*512 + wi, where wi = column-pair index (cols 2wi, 2wi+1).

__device__ __forceinline__ ushort f2bf(float f) {
    uint u = __float_as_uint(f);
    u += 0x7fffu + ((u >> 16) & 1u);   // RNE
    return (ushort)(u >> 16);
}
__device__ __forceinline__ float sigmoidf_(float x) { return 1.0f / (1.0f + expf(-x)); }

// ---------------- prep: fp32 -> bf16 converts, bias sums, h0 tagging ----------------
__global__ __launch_bounds__(256) void prep_kernel(
    const float* __restrict__ x,
    const float* __restrict__ wih_f, const float* __restrict__ whh_f,
    const float* __restrict__ bih_f, const float* __restrict__ bhh_f,
    const float* __restrict__ wih_b, const float* __restrict__ whh_b,
    const float* __restrict__ bih_b, const float* __restrict__ bhh_b,
    const float* __restrict__ h0f, const float* __restrict__ h0b,
    char* __restrict__ ws)
{
    int r = blockIdx.x * 256 + threadIdx.x;
    const int n_x = 16777216, n_w = 4194304;
    if (r < n_x) { ((ushort*)(ws + OFF_XB))[r] = f2bf(x[r]); return; }
    r -= n_x;
    if (r < n_w) { ((ushort*)(ws + OFF_WIH_F))[r] = f2bf(wih_f[r]); return; }
    r -= n_w;
    if (r < n_w) { ((ushort*)(ws + OFF_WIH_B))[r] = f2bf(wih_b[r]); return; }
    r -= n_w;
    if (r < n_w) { ((ushort*)(ws + OFF_WHH_F))[r] = f2bf(whh_f[r]); return; }
    r -= n_w;
    if (r < n_w) { ((ushort*)(ws + OFF_WHH_B))[r] = f2bf(whh_b[r]); return; }
    r -= n_w;
    if (r < 4096) { ((float*)(ws + OFF_BSUM_F))[r] = bih_f[r] + bhh_f[r]; return; }
    r -= 4096;
    if (r < 4096) { ((float*)(ws + OFF_BSUM_B))[r] = bih_b[r] + bhh_b[r]; return; }
    r -= 4096;
    if (r < 16384) {                       // dir0 parity0: h0f tagged 0
        int b = r >> 9, wi = r & 511;
        uint pay = (uint)f2bf(h0f[b * 1024 + wi * 2]) |
                   ((uint)f2bf(h0f[b * 1024 + wi * 2 + 1]) << 16);
        ((ull*)(ws + OFF_HBUF))[r] = (ull)pay;   // tag 0
        return;
    }
    r -= 16384;
    if (r < 16384) {                       // dir1 parity0: h0b tagged 0
        int b = r >> 9, wi = r & 511;
        uint pay = (uint)f2bf(h0b[b * 1024 + wi * 2]) |
                   ((uint)f2bf(h0b[b * 1024 + wi * 2 + 1]) << 16);
        ((ull*)(ws + OFF_HBUF))[2 * 16384 + r] = (ull)pay;
        return;
    }
    r -= 16384;
    if (r < 32768) {                       // parity1 both dirs: poison tag
        size_t wd = (r < 16384) ? (size_t)(16384 + r) : (size_t)(3 * 16384 + (r - 16384));
        ((ull*)(ws + OFF_HBUF))[wd] = 0xFFFFFFFF00000000ull;
        return;
    }
}

// ---------------- xg GEMM: xg[slot*32+b][g] = sum_i x[t][b][i] * Wih[g][i] ----------------
__global__ __launch_bounds__(256) void gemm_xg(
    const ushort* __restrict__ xb,
    const ushort* __restrict__ wihf, const ushort* __restrict__ wihb,
    _Float16* __restrict__ xgf, _Float16* __restrict__ xgb,
    int s0)
{
    __shared__ ushort As[128 * 32];
    __shared__ ushort Bs[128 * 32];
    const int dir = blockIdx.z;
    const ushort* __restrict__ W = dir ? wihb : wihf;
    _Float16* __restrict__ xg = dir ? xgb : xgf;
    const int mBlk = blockIdx.x, nBlk = blockIdx.y;
    const int tid = threadIdx.x;
    const int w = tid >> 6, l = tid & 63;
    const int q = l >> 4, ml = l & 15;

    f32x4 acc[4][4];
    const f32x4 zero = {0.f, 0.f, 0.f, 0.f};
#pragma unroll
    for (int i = 0; i < 4; ++i)
#pragma unroll
        for (int j = 0; j < 4; ++j) acc[i][j] = zero;

    for (int kb = 0; kb < 32; ++kb) {
#pragma unroll
        for (int it = 0; it < 2; ++it) {
            int idx = tid + 256 * it;           // 0..511
            int rl = idx >> 2, kc = idx & 3;
            int gr = mBlk * 128 + rl;           // row in slot-space
            int slot = gr >> 5, bb = gr & 31;
            int t = dir ? (511 - s0 - slot) : (s0 + slot);
            const ushort* ga = xb + (size_t)(t * 32 + bb) * 1024 + kb * 32 + kc * 8;
            __builtin_amdgcn_global_load_lds((cg_void*)ga, (lds_void*)(As + idx * 8), 16, 0, 0);
            int colg = nBlk * 128 + rl;
            const ushort* gbp = W + (size_t)colg * 1024 + kb * 32 + kc * 8;
            __builtin_amdgcn_global_load_lds((cg_void*)gbp, (lds_void*)(Bs + idx * 8), 16, 0, 0);
        }
        __syncthreads();
        short8 af[4], bfr[4];
#pragma unroll
        for (int i = 0; i < 4; ++i)
            af[i] = *(const short8*)(As + ((w & 1) * 64 + i * 16 + ml) * 32 + q * 8);
#pragma unroll
        for (int j = 0; j < 4; ++j)
            bfr[j] = *(const short8*)(Bs + ((w >> 1) * 64 + j * 16 + ml) * 32 + q * 8);
#pragma unroll
        for (int i = 0; i < 4; ++i)
#pragma unroll
            for (int j = 0; j < 4; ++j)
                acc[i][j] = __builtin_amdgcn_mfma_f32_16x16x32_bf16(af[i], bfr[j], acc[i][j], 0, 0, 0);
        __syncthreads();
    }
#pragma unroll
    for (int i = 0; i < 4; ++i)
#pragma unroll
        for (int j = 0; j < 4; ++j)
#pragma unroll
            for (int rr = 0; rr < 4; ++rr) {
                int row = mBlk * 128 + (w & 1) * 64 + i * 16 + q * 4 + rr;
                int col = nBlk * 128 + (w >> 1) * 64 + j * 16 + ml;
                xg[(size_t)row * 4096 + col] = (_Float16)acc[i][j][rr];
            }
}

// ---------------- recurrence: cooperative, 64 blocks x 512 threads ----------------
// dir = bx&1, p = bx>>1 (0..31). Block owns h-cols [p*32,(p+1)*32). Wave w: gate
// nt=w&3, K-half kh=w>>2; B-frags (32 cols x 512 K) persist in 128 VGPRs/lane.
// ROUND-3 protocol: tagged-word exchange. Producer stores (payload|tag s+1) per
// 8B word, fire-and-forget (no drain, no flags). Consumer spins per word on
// tag==s. Safety: at parity s&1 a slot holds only tag s-2 (stale) or s, because
// block B posting tag s+1 required tag-s words from ALL blocks, which required
// their tag-(s-1) reads to have completed -> no consumer can still want s-2.
__global__ __launch_bounds__(512, 1) void rec_kernel(
    const ushort* __restrict__ whhf, const ushort* __restrict__ whhb,
    const _Float16* __restrict__ xgf, const _Float16* __restrict__ xgb,
    const float* __restrict__ bsumf, const float* __restrict__ bsumb,
    const float* __restrict__ c0f, const float* __restrict__ c0b,
    ull* __restrict__ hbuf, float* __restrict__ cbuf,
    float* __restrict__ out,
    int s0, int csteps)
{
    __shared__ __align__(16) char lds_raw[65536];   // h-stage (64KB), overlaid by gate buf
    ushort* Hst = (ushort*)lds_raw;
    float*  gb  = (float*)lds_raw;

    const int bx = blockIdx.x;
    const int dir = bx & 1;
    const int p = bx >> 1;              // 0..31
    const int tid = threadIdx.x;
    const int w = tid >> 6;             // 0..7
    const int l = tid & 63;
    const int half = l >> 5;
    const int m32 = l & 31;
    const int nt = w & 3;               // gate index
    const int kh = w >> 2;              // K half

    const ushort* W = dir ? whhb : whhf;
    const _Float16* xg = dir ? xgb : xgf;
    const float* bsum = dir ? bsumb : bsumf;

    // B-frag preload: col = nt*1024 + p*32 + m32, k = kh*512 + kk*16 + half*8 + j
    const ushort* wrow = W + ((size_t)(nt * 1024 + p * 32 + m32)) * 1024 + kh * 512 + half * 8;
    short8 bfrag[32];
#pragma unroll
    for (int kk = 0; kk < 32; ++kk)
        bfrag[kk] = *(const short8*)(wrow + kk * 16);

    // elementwise identity: thread -> (batch b, col pair rp, rp+1)
    const int b = tid >> 4;             // 0..31
    const int rp = (tid & 15) * 2;      // 0,2,..,30
    const int hcol = p * 32 + rp;
    f32x2 bs[4];
#pragma unroll
    for (int g = 0; g < 4; ++g)
        bs[g] = *(const f32x2*)(bsum + g * 1024 + hcol);
    f32x2 cc;
    {
        const float* csrc = (s0 == 0) ? (dir ? c0b : c0f) : (cbuf + dir * 32768);
        cc = *(const f32x2*)(csrc + b * 1024 + hcol);
    }

    const int ch = tid >> 2;            // 16B chunk index for staging ds_writes
    const int sub = (tid & 3) * 2;      // ushort sub-offset within chunk

    for (int s = s0; s < s0 + csteps; ++s) {
        const int slot = s - s0;
        const int t = dir ? (511 - s) : s;

        // xg for this step: issued first, hidden under staging + MFMA
        uint xv[4];
#pragma unroll
        for (int g = 0; g < 4; ++g)
            xv[g] = *(const uint*)(xg + ((size_t)slot * 32 + b) * 4096 + g * 1024 + hcol);

        // ---- stage h^s: 32 tagged words/lane, pipelined 4 groups of 8 ----
        const ull* hb64 = hbuf + (size_t)(dir * 2 + (s & 1)) * 16384;
        const uint su = (uint)s;
        {
            ull cur[8], nxt[8];
#pragma unroll
            for (int j = 0; j < 8; ++j)
                cur[j] = __hip_atomic_load(hb64 + j * 512 + tid,
                                           __ATOMIC_RELAXED, __HIP_MEMORY_SCOPE_AGENT);
#pragma unroll
            for (int gI = 0; gI < 4; ++gI) {
                if (gI < 3) {
#pragma unroll
                    for (int j = 0; j < 8; ++j)
                        nxt[j] = __hip_atomic_load(hb64 + (gI * 8 + 8 + j) * 512 + tid,
                                                   __ATOMIC_RELAXED, __HIP_MEMORY_SCOPE_AGENT);
                }
                for (;;) {
                    bool bad = false;
#pragma unroll
                    for (int j = 0; j < 8; ++j)
                        bad = bad || ((uint)(cur[j] >> 32) != su);
                    if (!__any(bad)) break;
#pragma unroll
                    for (int j = 0; j < 8; ++j)
                        if ((uint)(cur[j] >> 32) != su)
                            cur[j] = __hip_atomic_load(hb64 + (gI * 8 + j) * 512 + tid,
                                                       __ATOMIC_RELAXED, __HIP_MEMORY_SCOPE_AGENT);
                }
#pragma unroll
                for (int j = 0; j < 8; ++j) {
                    const int bb = gI * 8 + j;   // batch row
                    *(uint*)(Hst + bb * 1024 + ((ch ^ (bb & 7)) << 3) + sub) = (uint)cur[j];
                }
                if (gI < 3) {
#pragma unroll
                    for (int j = 0; j < 8; ++j) cur[j] = nxt[j];
                }
            }
        }
        __syncthreads();

        // ---- MFMA: gates[32 batch, 32 cols] partial over K-half ----
        f32x16 acce, acco;
#pragma unroll
        for (int i = 0; i < 16; ++i) { acce[i] = 0.f; acco[i] = 0.f; }
#pragma unroll
        for (int kk = 0; kk < 32; kk += 2) {
            const short8 a0 = *(const short8*)(Hst + m32 * 1024 +
                (((kh * 64 + kk * 2 + half) ^ (m32 & 7)) << 3));
            acce = __builtin_amdgcn_mfma_f32_32x32x16_bf16(a0, bfrag[kk], acce, 0, 0, 0);
            const short8 a1 = *(const short8*)(Hst + m32 * 1024 +
                (((kh * 64 + (kk + 1) * 2 + half) ^ (m32 & 7)) << 3));
            acco = __builtin_amdgcn_mfma_f32_32x32x16_bf16(a1, bfrag[kk + 1], acco, 0, 0, 0);
        }
        __syncthreads();   // all Hst reads done before gbuf overlay writes

        // ---- C-store: row=(reg&3)+8*(reg>>2)+4*half, col=m32 ----
#pragma unroll
        for (int reg = 0; reg < 16; ++reg) {
            const int row = (reg & 3) + 8 * (reg >> 2) + 4 * half;
            gb[kh * 4128 + row * 129 + nt * 32 + m32] = acce[reg] + acco[reg];
        }
        __syncthreads();

        // ---- elementwise LSTM update (2 adjacent cols, 1 batch per thread) ----
        const float* gA = gb + b * 129 + rp;
        const float* gB = gb + 4128 + b * 129 + rp;
        f32x2 G[4];
#pragma unroll
        for (int g = 0; g < 4; ++g) {
            h2f xh = __builtin_bit_cast(h2f, xv[g]);
            G[g][0] = gA[g * 32]     + gB[g * 32]     + bs[g][0] + (float)xh[0];
            G[g][1] = gA[g * 32 + 1] + gB[g * 32 + 1] + bs[g][1] + (float)xh[1];
        }
        f32x2 hh;
#pragma unroll
        for (int j = 0; j < 2; ++j) {
            float ii = sigmoidf_(G[0][j]), ff2 = sigmoidf_(G[1][j]);
            float g2 = tanhf(G[2][j]),     oo  = sigmoidf_(G[3][j]);
            cc[j] = ff2 * cc[j] + ii * g2;
            hh[j] = oo * tanhf(cc[j]);
        }
        // ---- tagged h store: fire-and-forget, self-validating ----
        {
            uint pay = (uint)f2bf(hh[0]) | ((uint)f2bf(hh[1]) << 16);
            ull word = (ull)pay | ((ull)(uint)(s + 1) << 32);
            __hip_atomic_store(hbuf + (size_t)(dir * 2 + ((s + 1) & 1)) * 16384 +
                                   b * 512 + p * 16 + (tid & 15),
                               word, __ATOMIC_RELAXED, __HIP_MEMORY_SCOPE_AGENT);
        }

        // ---- out stores (off the critical path, nontemporal: keep L2 clean) ----
        __builtin_nontemporal_store(__builtin_bit_cast(double, hh),
            (double*)(out + (size_t)t * 65536 + b * 2048 + dir * 1024 + hcol));
        if (s == 511) {
            float* fin = out + 33554432 + dir * 65536;   // hf,cf then hb,cb
            *(f32x2*)(fin + b * 1024 + hcol) = hh;
            *(f32x2*)(fin + 32768 + b * 1024 + hcol) = cc;
        }
        __syncthreads();   // gb reads done before next iter's Hst staging writes
    }
    *(f32x2*)(cbuf + dir * 32768 + b * 1024 + hcol) = cc;
}

// ---------------- host ----------------
extern "C" void kernel_launch(void* const* d_in, const int* in_sizes, int n_in,
                              void* d_out, int out_size, void* d_ws, size_t ws_size,
                              hipStream_t stream)
{
    const float* x     = (const float*)d_in[0];
    const float* h0f   = (const float*)d_in[1];
    const float* c0f   = (const float*)d_in[2];
    const float* h0b   = (const float*)d_in[3];
    const float* c0b   = (const float*)d_in[4];
    const float* wih_f = (const float*)d_in[5];
    const float* whh_f = (const float*)d_in[6];
    const float* bih_f = (const float*)d_in[7];
    const float* bhh_f = (const float*)d_in[8];
    const float* wih_b = (const float*)d_in[9];
    const float* whh_b = (const float*)d_in[10];
    const float* bih_b = (const float*)d_in[11];
    const float* bhh_b = (const float*)d_in[12];
    float* out = (float*)d_out;
    char* ws = (char*)d_ws;

    int csteps = 16;
    const int cands[6] = {512, 256, 128, 64, 32, 16};
    for (int i = 0; i < 6; ++i) {
        size_t need = OFF_XG + 2ull * (size_t)cands[i] * 262144ull;
        if (need <= ws_size) { csteps = cands[i]; break; }
    }

    // total prep threads: 16777216 + 4*4194304 + 2*4096 + 2*16384 + 32768 = 33628160
    prep_kernel<<<131360, 256, 0, stream>>>(x, wih_f, whh_f, bih_f, bhh_f,
                                            wih_b, whh_b, bih_b, bhh_b, h0f, h0b, ws);

    const ushort* xb    = (const ushort*)(ws + OFF_XB);
    const ushort* wihfb = (const ushort*)(ws + OFF_WIH_F);
    const ushort* wihbb = (const ushort*)(ws + OFF_WIH_B);
    const ushort* whhfb = (const ushort*)(ws + OFF_WHH_F);
    const ushort* whhbb = (const ushort*)(ws + OFF_WHH_B);
    const float*  bsf   = (const float*)(ws + OFF_BSUM_F);
    const float*  bsb   = (const float*)(ws + OFF_BSUM_B);
    ull*    hb          = (ull*)(ws + OFF_HBUF);
    float*  cb          = (float*)(ws + OFF_CBUF);
    _Float16* xgfp      = (_Float16*)(ws + OFF_XG);
    _Float16* xgbp      = (_Float16*)(ws + OFF_XG + (size_t)csteps * 262144ull);

    const int nchunks = 512 / csteps;
    for (int cidx = 0; cidx < nchunks; ++cidx) {
        int s0 = cidx * csteps;
        gemm_xg<<<dim3(csteps / 4, 32, 2), 256, 0, stream>>>(xb, wihfb, wihbb, xgfp, xgbp, s0);

        const ushort* a0 = whhfb; const ushort* a1 = whhbb;
        const _Float16* a2 = xgfp; const _Float16* a3 = xgbp;
        const float* a4 = bsf; const float* a5 = bsb;
        const float* a6 = c0f; const float* a7 = c0b;
        ull* a8 = hb; float* a9 = cb; float* a10 = out;
        int a11 = s0, a12 = csteps;
        void* args[] = {&a0, &a1, &a2, &a3, &a4, &a5, &a6, &a7, &a8, &a9, &a10, &a11, &a12};
        hipLaunchCooperativeKernel((void*)rec_kernel, dim3(64), dim3(512), args, 0, stream);
    }
}

// Round 4
// 3001.186 us; speedup vs baseline: 1.4422x; 1.1990x over previous
//
#include <hip/hip_runtime.h>
#include <stdint.h>

// T=512, B=32, I=1024, H=1024, G=4H=4096
// out: [512][32][2048] fp32 then hf[32][1024], cf, hb, cb  (total 33685504 f32)

using short8 = __attribute__((ext_vector_type(8))) short;   // 8 bf16
using f32x4  = __attribute__((ext_vector_type(4))) float;
using f32x2  = __attribute__((ext_vector_type(2))) float;
using f32x16 = __attribute__((ext_vector_type(16))) float;
using h2f    = __attribute__((ext_vector_type(2))) _Float16;

typedef unsigned int uint;
typedef unsigned short ushort;
typedef unsigned long long ull;

typedef const __attribute__((address_space(1))) void cg_void;
typedef __attribute__((address_space(3))) void lds_void;

// ---------------- ws layout (bytes) ----------------
// ROUND-4: gemm_xg is FUSED into the cooperative launch: blocks 0..63 = rec
// (round-3 verified tagged-word exchange, untouched), blocks 64..255 = xg-GEMM
// producers on the previously-idle 192 CUs. Producers post per-(dir,mg) tile
// counters (mg = 4-step group); rec guard-polls once per mg. Removes the
// ~550us serial gemm phase. Also: libm expf/tanhf -> raw v_exp/v_rcp.
#define OFF_XB      0ull            // x as bf16: 16777216 * 2 = 33554432
#define OFF_WIH_F   33554432ull     // 4096*1024*2 = 8388608
#define OFF_WIH_B   41943040ull
#define OFF_WHH_F   50331648ull
#define OFF_WHH_B   58720256ull
#define OFF_BSUM_F  67108864ull     // 4096 * 4
#define OFF_BSUM_B  67125248ull
#define OFF_HBUF    67141632ull     // 2 dir * 2 parity * 16384 tagged ull = 524288
#define OFF_XGCNT   67665920ull     // 2 dir * 128 mg counters = 1024B
#define OFF_XG      67667968ull     // fp16 xg: 2 * 512*32*4096*2 = 268435456

__device__ __forceinline__ ushort f2bf(float f) {
    uint u = __float_as_uint(f);
    u += 0x7fffu + ((u >> 16) & 1u);   // RNE
    return (ushort)(u >> 16);
}
// fast activations: v_exp_f32 is 2^x; rcp ~1ulp. Saturation-safe (exp2->inf
// -> rcp->0). |err| ~1e-7 << 7.8e-3 tolerance.
__device__ __forceinline__ float fsig(float x) {
    float e = __builtin_amdgcn_exp2f(-1.4426950408889634f * x);
    return __builtin_amdgcn_rcpf(1.0f + e);
}
__device__ __forceinline__ float ftanh(float x) {
    float e = __builtin_amdgcn_exp2f(2.8853900817779268f * x);
    return 1.0f - 2.0f * __builtin_amdgcn_rcpf(1.0f + e);
}

// ---------------- prep: fp32 -> bf16 converts, bias sums, h0 tagging ----------------
__global__ __launch_bounds__(256) void prep_kernel(
    const float* __restrict__ x,
    const float* __restrict__ wih_f, const float* __restrict__ whh_f,
    const float* __restrict__ bih_f, const float* __restrict__ bhh_f,
    const float* __restrict__ wih_b, const float* __restrict__ whh_b,
    const float* __restrict__ bih_b, const float* __restrict__ bhh_b,
    const float* __restrict__ h0f, const float* __restrict__ h0b,
    char* __restrict__ ws)
{
    int r = blockIdx.x * 256 + threadIdx.x;
    const int n_x = 16777216, n_w = 4194304;
    if (r < n_x) { ((ushort*)(ws + OFF_XB))[r] = f2bf(x[r]); return; }
    r -= n_x;
    if (r < n_w) { ((ushort*)(ws + OFF_WIH_F))[r] = f2bf(wih_f[r]); return; }
    r -= n_w;
    if (r < n_w) { ((ushort*)(ws + OFF_WIH_B))[r] = f2bf(wih_b[r]); return; }
    r -= n_w;
    if (r < n_w) { ((ushort*)(ws + OFF_WHH_F))[r] = f2bf(whh_f[r]); return; }
    r -= n_w;
    if (r < n_w) { ((ushort*)(ws + OFF_WHH_B))[r] = f2bf(whh_b[r]); return; }
    r -= n_w;
    if (r < 4096) { ((float*)(ws + OFF_BSUM_F))[r] = bih_f[r] + bhh_f[r]; return; }
    r -= 4096;
    if (r < 4096) { ((float*)(ws + OFF_BSUM_B))[r] = bih_b[r] + bhh_b[r]; return; }
    r -= 4096;
    if (r < 16384) {                       // dir0 parity0: h0f tagged 0
        int b = r >> 9, wi = r & 511;
        uint pay = (uint)f2bf(h0f[b * 1024 + wi * 2]) |
                   ((uint)f2bf(h0f[b * 1024 + wi * 2 + 1]) << 16);
        ((ull*)(ws + OFF_HBUF))[r] = (ull)pay;   // tag 0
        return;
    }
    r -= 16384;
    if (r < 16384) {                       // dir1 parity0: h0b tagged 0
        int b = r >> 9, wi = r & 511;
        uint pay = (uint)f2bf(h0b[b * 1024 + wi * 2]) |
                   ((uint)f2bf(h0b[b * 1024 + wi * 2 + 1]) << 16);
        ((ull*)(ws + OFF_HBUF))[2 * 16384 + r] = (ull)pay;
        return;
    }
    r -= 16384;
    if (r < 32768) {                       // parity1 both dirs: poison tag
        size_t wd = (r < 16384) ? (size_t)(16384 + r) : (size_t)(3 * 16384 + (r - 16384));
        ((ull*)(ws + OFF_HBUF))[wd] = 0xFFFFFFFF00000000ull;
        return;
    }
    r -= 32768;
    if (r < 256) { ((uint*)(ws + OFF_XGCNT))[r] = 0u; return; }
}

// ---------------- fused cooperative kernel: 256 blocks x 512 threads ----------------
// blocks 0..63:   rec (dir = bx&1, p = bx>>1): round-3 tagged-word exchange.
// blocks 64..255: xg producers. Tile = 128 rows (4 slots x 32 batch) x 256 gate
//   cols, K=1024. tau = mg*32 + dir*16 + n processed round-robin over 192
//   blocks in mg-ascending order, so early steps complete first. After the
//   tile's agent-scope stores drain, one lane bumps xgcnt[dir*128+mg]; a group
//   is ready when its counter reaches 16.
__global__ __launch_bounds__(512, 1) void fused_kernel(
    const ushort* __restrict__ whhf, const ushort* __restrict__ whhb,
    const ushort* __restrict__ xb,
    const ushort* __restrict__ wihf, const ushort* __restrict__ wihb,
    _Float16* __restrict__ xgf, _Float16* __restrict__ xgb,
    const float* __restrict__ bsumf, const float* __restrict__ bsumb,
    const float* __restrict__ c0f, const float* __restrict__ c0b,
    ull* __restrict__ hbuf, float* __restrict__ out,
    uint* __restrict__ xgcnt)
{
    __shared__ __align__(16) char lds_raw[65536];
    const int tid = threadIdx.x;
    const int w = tid >> 6;             // 0..7
    const int l = tid & 63;

    if (blockIdx.x >= 64) {
        // ================= xg producer =================
        const int g = blockIdx.x - 64;  // 0..191
        ushort* As = (ushort*)lds_raw;          // [128][32]
        ushort* Bs = (ushort*)lds_raw + 4096;   // [256][32]
        const int q = l >> 4, ml = l & 15;

        for (int tau = g; tau < 4096; tau += 192) {
            const int mg = tau >> 5, dir = (tau >> 4) & 1, n = tau & 15;
            const ushort* Wn = (dir ? wihb : wihf) + (size_t)(n * 256) * 1024;
            _Float16* xgd = dir ? xgb : xgf;

            f32x4 acc[4][4];
            const f32x4 zero = {0.f, 0.f, 0.f, 0.f};
#pragma unroll
            for (int i = 0; i < 4; ++i)
#pragma unroll
                for (int j = 0; j < 4; ++j) acc[i][j] = zero;

            for (int kb = 0; kb < 32; ++kb) {
                {   // stage A: 512 chunks of 16B
                    int rl = tid >> 2, kc = tid & 3;
                    int slot = mg * 4 + (rl >> 5), bb = rl & 31;
                    int t = dir ? (511 - slot) : slot;
                    const ushort* ga = xb + (size_t)(t * 32 + bb) * 1024 + kb * 32 + kc * 8;
                    __builtin_amdgcn_global_load_lds((cg_void*)ga, (lds_void*)(As + tid * 8), 16, 0, 0);
                }
#pragma unroll
                for (int it = 0; it < 2; ++it) {   // stage B: 1024 chunks
                    int idx = tid + 512 * it;
                    int rl = idx >> 2, kc = idx & 3;
                    const ushort* gbp = Wn + (size_t)rl * 1024 + kb * 32 + kc * 8;
                    __builtin_amdgcn_global_load_lds((cg_void*)gbp, (lds_void*)(Bs + idx * 8), 16, 0, 0);
                }
                __syncthreads();
                short8 af[4], bfr[4];
#pragma unroll
                for (int i = 0; i < 4; ++i)
                    af[i] = *(const short8*)(As + ((w & 1) * 64 + i * 16 + ml) * 32 + q * 8);
#pragma unroll
                for (int j = 0; j < 4; ++j)
                    bfr[j] = *(const short8*)(Bs + ((w >> 1) * 64 + j * 16 + ml) * 32 + q * 8);
#pragma unroll
                for (int i = 0; i < 4; ++i)
#pragma unroll
                    for (int j = 0; j < 4; ++j)
                        acc[i][j] = __builtin_amdgcn_mfma_f32_16x16x32_bf16(af[i], bfr[j], acc[i][j], 0, 0, 0);
                __syncthreads();
            }
            // epilogue: agent-scope (write-through) fp16 stores, then drain+count
            ushort* xgu = (ushort*)xgd;
#pragma unroll
            for (int i = 0; i < 4; ++i)
#pragma unroll
                for (int j = 0; j < 4; ++j)
#pragma unroll
                    for (int rr = 0; rr < 4; ++rr) {
                        int trow = (w & 1) * 64 + i * 16 + q * 4 + rr;
                        int col = n * 256 + (w >> 1) * 64 + j * 16 + ml;
                        size_t grow = (size_t)(mg * 128 + trow);
                        _Float16 v = (_Float16)acc[i][j][rr];
                        __hip_atomic_store(xgu + grow * 4096 + col,
                                           __builtin_bit_cast(ushort, v),
                                           __ATOMIC_RELAXED, __HIP_MEMORY_SCOPE_AGENT);
                    }
            asm volatile("s_waitcnt vmcnt(0)" ::: "memory");
            __syncthreads();
            if (tid == 0)
                __hip_atomic_fetch_add(xgcnt + dir * 128 + mg, 1u,
                                       __ATOMIC_RELAXED, __HIP_MEMORY_SCOPE_AGENT);
        }
        return;
    }

    // ================= rec =================
    __builtin_amdgcn_s_setprio(1);
    ushort* Hst = (ushort*)lds_raw;
    float*  gb  = (float*)lds_raw;

    const int bx = blockIdx.x;
    const int dir = bx & 1;
    const int p = bx >> 1;              // 0..31
    const int half = l >> 5;
    const int m32 = l & 31;
    const int nt = w & 3;               // gate index
    const int kh = w >> 2;              // K half

    const ushort* W = dir ? whhb : whhf;
    const _Float16* xg = dir ? xgb : xgf;
    const float* bsum = dir ? bsumb : bsumf;
    const uint* xcnt = xgcnt + dir * 128;

    // B-frag preload: col = nt*1024 + p*32 + m32, k = kh*512 + kk*16 + half*8 + j
    const ushort* wrow = W + ((size_t)(nt * 1024 + p * 32 + m32)) * 1024 + kh * 512 + half * 8;
    short8 bfrag[32];
#pragma unroll
    for (int kk = 0; kk < 32; ++kk)
        bfrag[kk] = *(const short8*)(wrow + kk * 16);

    // elementwise identity: thread -> (batch b, col pair rp, rp+1)
    const int b = tid >> 4;             // 0..31
    const int rp = (tid & 15) * 2;      // 0,2,..,30
    const int hcol = p * 32 + rp;
    f32x2 bs[4];
#pragma unroll
    for (int g2 = 0; g2 < 4; ++g2)
        bs[g2] = *(const f32x2*)(bsum + g2 * 1024 + hcol);
    f32x2 cc;
    {
        const float* csrc = dir ? c0b : c0f;
        cc = *(const f32x2*)(csrc + b * 1024 + hcol);
    }

    const int ch = tid >> 2;            // 16B chunk index for staging ds_writes
    const int sub = (tid & 3) * 2;      // ushort sub-offset within chunk

    for (int s = 0; s < 512; ++s) {
        const int t = dir ? (511 - s) : s;

        // xg guard poll (once per 4-step group; producers run ~2-3x ahead)
        if ((s & 3) == 0) {
            const uint* cp = xcnt + (s >> 2);
            uint c = __hip_atomic_load(cp, __ATOMIC_RELAXED, __HIP_MEMORY_SCOPE_AGENT);
            while (c < 16u) {
                __builtin_amdgcn_s_sleep(8);
                c = __hip_atomic_load(cp, __ATOMIC_RELAXED, __HIP_MEMORY_SCOPE_AGENT);
            }
        }

        // xg for this step: issued first, hidden under staging + MFMA
        uint xv[4];
#pragma unroll
        for (int g2 = 0; g2 < 4; ++g2)
            xv[g2] = __hip_atomic_load(
                (const uint*)(xg + ((size_t)s * 32 + b) * 4096 + g2 * 1024 + hcol),
                __ATOMIC_RELAXED, __HIP_MEMORY_SCOPE_AGENT);

        // ---- stage h^s: 32 tagged words/lane, pipelined 4 groups of 8 ----
        const ull* hb64 = hbuf + (size_t)(dir * 2 + (s & 1)) * 16384;
        const uint su = (uint)s;
        {
            ull cur[8], nxt[8];
#pragma unroll
            for (int j = 0; j < 8; ++j)
                cur[j] = __hip_atomic_load(hb64 + j * 512 + tid,
                                           __ATOMIC_RELAXED, __HIP_MEMORY_SCOPE_AGENT);
#pragma unroll
            for (int gI = 0; gI < 4; ++gI) {
                if (gI < 3) {
#pragma unroll
                    for (int j = 0; j < 8; ++j)
                        nxt[j] = __hip_atomic_load(hb64 + (gI * 8 + 8 + j) * 512 + tid,
                                                   __ATOMIC_RELAXED, __HIP_MEMORY_SCOPE_AGENT);
                }
                for (;;) {
                    bool bad = false;
#pragma unroll
                    for (int j = 0; j < 8; ++j)
                        bad = bad || ((uint)(cur[j] >> 32) != su);
                    if (!__any(bad)) break;
#pragma unroll
                    for (int j = 0; j < 8; ++j)
                        if ((uint)(cur[j] >> 32) != su)
                            cur[j] = __hip_atomic_load(hb64 + (gI * 8 + j) * 512 + tid,
                                                       __ATOMIC_RELAXED, __HIP_MEMORY_SCOPE_AGENT);
                }
#pragma unroll
                for (int j = 0; j < 8; ++j) {
                    const int bb = gI * 8 + j;   // batch row
                    *(uint*)(Hst + bb * 1024 + ((ch ^ (bb & 7)) << 3) + sub) = (uint)cur[j];
                }
                if (gI < 3) {
#pragma unroll
                    for (int j = 0; j < 8; ++j) cur[j] = nxt[j];
                }
            }
        }
        __syncthreads();

        // ---- MFMA: gates[32 batch, 32 cols] partial over K-half ----
        f32x16 acce, acco;
#pragma unroll
        for (int i = 0; i < 16; ++i) { acce[i] = 0.f; acco[i] = 0.f; }
#pragma unroll
        for (int kk = 0; kk < 32; kk += 2) {
            const short8 a0 = *(const short8*)(Hst + m32 * 1024 +
                (((kh * 64 + kk * 2 + half) ^ (m32 & 7)) << 3));
            acce = __builtin_amdgcn_mfma_f32_32x32x16_bf16(a0, bfrag[kk], acce, 0, 0, 0);
            const short8 a1 = *(const short8*)(Hst + m32 * 1024 +
                (((kh * 64 + (kk + 1) * 2 + half) ^ (m32 & 7)) << 3));
            acco = __builtin_amdgcn_mfma_f32_32x32x16_bf16(a1, bfrag[kk + 1], acco, 0, 0, 0);
        }
        __syncthreads();   // all Hst reads done before gbuf overlay writes

        // ---- C-store: row=(reg&3)+8*(reg>>2)+4*half, col=m32 ----
#pragma unroll
        for (int reg = 0; reg < 16; ++reg) {
            const int row = (reg & 3) + 8 * (reg >> 2) + 4 * half;
            gb[kh * 4128 + row * 129 + nt * 32 + m32] = acce[reg] + acco[reg];
        }
        __syncthreads();

        // ---- elementwise LSTM update (2 adjacent cols, 1 batch per thread) ----
        const float* gA = gb + b * 129 + rp;
        const float* gB = gb + 4128 + b * 129 + rp;
        f32x2 G[4];
#pragma unroll
        for (int g2 = 0; g2 < 4; ++g2) {
            h2f xh = __builtin_bit_cast(h2f, xv[g2]);
            G[g2][0] = gA[g2 * 32]     + gB[g2 * 32]     + bs[g2][0] + (float)xh[0];
            G[g2][1] = gA[g2 * 32 + 1] + gB[g2 * 32 + 1] + bs[g2][1] + (float)xh[1];
        }
        f32x2 hh;
#pragma unroll
        for (int j = 0; j < 2; ++j) {
            float ii = fsig(G[0][j]), ff2 = fsig(G[1][j]);
            float g2v = ftanh(G[2][j]), oo = fsig(G[3][j]);
            cc[j] = ff2 * cc[j] + ii * g2v;
            hh[j] = oo * ftanh(cc[j]);
        }
        // ---- tagged h store: fire-and-forget, self-validating ----
        {
            uint pay = (uint)f2bf(hh[0]) | ((uint)f2bf(hh[1]) << 16);
            ull word = (ull)pay | ((ull)(uint)(s + 1) << 32);
            __hip_atomic_store(hbuf + (size_t)(dir * 2 + ((s + 1) & 1)) * 16384 +
                                   b * 512 + p * 16 + (tid & 15),
                               word, __ATOMIC_RELAXED, __HIP_MEMORY_SCOPE_AGENT);
        }

        // ---- out stores (off the critical path, nontemporal: keep L2 clean) ----
        __builtin_nontemporal_store(__builtin_bit_cast(double, hh),
            (double*)(out + (size_t)t * 65536 + b * 2048 + dir * 1024 + hcol));
        if (s == 511) {
            float* fin = out + 33554432 + dir * 65536;   // hf,cf then hb,cb
            *(f32x2*)(fin + b * 1024 + hcol) = hh;
            *(f32x2*)(fin + 32768 + b * 1024 + hcol) = cc;
        }
        __syncthreads();   // gb reads done before next iter's Hst staging writes
    }
}

// ---------------- host ----------------
extern "C" void kernel_launch(void* const* d_in, const int* in_sizes, int n_in,
                              void* d_out, int out_size, void* d_ws, size_t ws_size,
                              hipStream_t stream)
{
    const float* x     = (const float*)d_in[0];
    const float* h0f   = (const float*)d_in[1];
    const float* c0f   = (const float*)d_in[2];
    const float* h0b   = (const float*)d_in[3];
    const float* c0b   = (const float*)d_in[4];
    const float* wih_f = (const float*)d_in[5];
    const float* whh_f = (const float*)d_in[6];
    const float* bih_f = (const float*)d_in[7];
    const float* bhh_f = (const float*)d_in[8];
    const float* wih_b = (const float*)d_in[9];
    const float* whh_b = (const float*)d_in[10];
    const float* bih_b = (const float*)d_in[11];
    const float* bhh_b = (const float*)d_in[12];
    float* out = (float*)d_out;
    char* ws = (char*)d_ws;

    // prep threads: 16777216 + 4*4194304 + 2*4096 + 2*16384 + 32768 + 256 = 33628416
    prep_kernel<<<131361, 256, 0, stream>>>(x, wih_f, whh_f, bih_f, bhh_f,
                                            wih_b, whh_b, bih_b, bhh_b, h0f, h0b, ws);

    const ushort* xbp   = (const ushort*)(ws + OFF_XB);
    const ushort* wihfb = (const ushort*)(ws + OFF_WIH_F);
    const ushort* wihbb = (const ushort*)(ws + OFF_WIH_B);
    const ushort* whhfb = (const ushort*)(ws + OFF_WHH_F);
    const ushort* whhbb = (const ushort*)(ws + OFF_WHH_B);
    const float*  bsf   = (const float*)(ws + OFF_BSUM_F);
    const float*  bsb   = (const float*)(ws + OFF_BSUM_B);
    ull*    hb          = (ull*)(ws + OFF_HBUF);
    uint*   xgcntp      = (uint*)(ws + OFF_XGCNT);
    _Float16* xgfp      = (_Float16*)(ws + OFF_XG);
    _Float16* xgbp      = (_Float16*)(ws + OFF_XG + 134217728ull);

    const ushort* a0 = whhfb; const ushort* a1 = whhbb;
    const ushort* a2 = xbp;
    const ushort* a3 = wihfb; const ushort* a4 = wihbb;
    _Float16* a5 = xgfp; _Float16* a6 = xgbp;
    const float* a7 = bsf; const float* a8 = bsb;
    const float* a9 = c0f; const float* a10 = c0b;
    ull* a11 = hb; float* a12 = out; uint* a13 = xgcntp;
    void* args[] = {&a0, &a1, &a2, &a3, &a4, &a5, &a6, &a7, &a8, &a9, &a10,
                    &a11, &a12, &a13};
    hipLaunchCooperativeKernel((void*)fused_kernel, dim3(256), dim3(512), args, 0, stream);
}